// Round 6
// baseline (556.896 us; speedup 1.0000x reference)
//
#include <hip/hip_runtime.h>
#include <hip/hip_bf16.h>
#include <cstdint>

// B=2, T=2048, HID=1024, H=16, DK=DV=64, K(conv)=4. fp32 in/out.
// RICH layout (ws >= 40MB): ws = 5 bf16 planes P0..P4 (8 MB each).
//   d_out scratch: xb bf16 [0,8M) (dead after g/beta GEMMs);
//   betab fp32 [16][4096] at [0,256K); G at [256K,512K); ob bf16 at [8M,16M).
// Pipeline: cvt -> mega_gemm(zq,zk,zv,a) -> conv q/k/v (vectorized x8)
//   -> g-GEMM -> beta-GEMM -> kk -> scan -> ln_gate -> final GEMM.
//
// Scan: look-ahead transform (serial chain = 1 fma/step) + chunk-bulk LDS.
// R5 post-mortem: asm pin on ARRAY elements failed (arrays never became SSA;
// VGPR stuck at 88 = impossible if 112 pinned regs were live). This version
// uses 28 NAMED variables + explicit 16-step macro expansion (zero arrays,
// all word indices constant) + asm "+v" pin. Falsifier: VGPR must rise ~160+.

using bf16 = __hip_bfloat16;
typedef __bf16 bf16x8 __attribute__((ext_vector_type(8)));
typedef __bf16 bf16x4v __attribute__((ext_vector_type(4)));
typedef float f32x4 __attribute__((ext_vector_type(4)));
typedef float f32x2 __attribute__((ext_vector_type(2)));
typedef unsigned int u32x4 __attribute__((ext_vector_type(4)));
typedef unsigned int u32x2 __attribute__((ext_vector_type(2)));

__device__ __forceinline__ __bf16 cvt_bf16(float f) {
  __hip_bfloat16 h = (__hip_bfloat16)f;
  return *reinterpret_cast<__bf16*>(&h);
}
__device__ __forceinline__ void async_copy16(const void* g, void* l) {
  __builtin_amdgcn_global_load_lds((const __attribute__((address_space(1))) void*)g,
                                   (__attribute__((address_space(3))) void*)l,
                                   16, 0, 0);
}
__device__ __forceinline__ float bcf(unsigned int u) { return __builtin_bit_cast(float, u); }
template <int CTRL>
__device__ __forceinline__ float dpp_f(float x) {
  int y = __builtin_amdgcn_update_dpp(0, __builtin_bit_cast(int, x), CTRL, 0xF, 0xF, true);
  return __builtin_bit_cast(float, y);
}

// fp32 -> bf16 plane (4M elements)
__global__ __launch_bounds__(256) void cvt_plane_kernel(
    const float* __restrict__ in, bf16* __restrict__ out)
{
  size_t i = ((size_t)blockIdx.x * 256 + threadIdx.x) * 4;
  float4 f = *(const float4*)(in + i);
  bf16x4v t;
  t[0] = cvt_bf16(f.x); t[1] = cvt_bf16(f.y); t[2] = cvt_bf16(f.z); t[3] = cvt_bf16(f.w);
  *(bf16x4v*)((__bf16*)out + i) = t;
}

// C = A * Bt^T. A: MxK (bf16 async-staged unless A_FP32); Bt: NxK fp32.
// MODE 2: raw->bf16; 3: sigmoid(acc+bias)->bf16; 4: raw->fp32; 5: sigmoid(acc+bias)->fp32 TRANSPOSED
template <int MODE, bool A_FP32>
__global__ __launch_bounds__(256) void gemm_bt(
    const void* __restrict__ Av, const float* __restrict__ Bt,
    const float* __restrict__ bias, float* __restrict__ Cf, bf16* __restrict__ Cb,
    int M, int N, int K)
{
  __shared__ __align__(16) __bf16 As[128 * 32];
  __shared__ __align__(16) __bf16 Bs[128 * 32];

  const int tid  = threadIdx.x;
  const int lane = tid & 63;
  const int wave = tid >> 6;
  const int tile_m = blockIdx.y * 128;
  const int tile_n = blockIdx.x * 128;
  const int wm = (wave >> 1) * 64;
  const int wn = (wave & 1) * 64;

  const int srow = lane >> 2;
  const int scol = (lane & 3) * 8;

  f32x4 acc[4][4];
#pragma unroll
  for (int i = 0; i < 4; ++i)
#pragma unroll
    for (int j = 0; j < 4; ++j) acc[i][j] = {0.f, 0.f, 0.f, 0.f};

  for (int k0 = 0; k0 < K; k0 += 32) {
    float4 b0[2], b1[2], a0[2], a1[2];
#pragma unroll
    for (int s = 0; s < 2; ++s) {
      int brow = tile_n + s * 64 + wave * 16 + srow;
      if (brow > N - 1) brow = N - 1;             // clamp (beta GEMM: N=16)
      const float* bp = Bt + (size_t)brow * K + k0 + scol;
      b0[s] = *(const float4*)bp;
      b1[s] = *(const float4*)(bp + 4);
      if (A_FP32) {
        int arow = tile_m + s * 64 + wave * 16 + srow;
        const float* ap = (const float*)Av + (size_t)arow * K + k0 + scol;
        a0[s] = *(const float4*)ap;
        a1[s] = *(const float4*)(ap + 4);
      }
    }
    __syncthreads();
#pragma unroll
    for (int s = 0; s < 2; ++s) {
      if (!A_FP32) {
        int arow = tile_m + s * 64 + wave * 16 + srow;
        async_copy16((const __bf16*)Av + (size_t)arow * K + k0 + scol,
                     &As[(s * 64 + wave * 16 + srow) * 32 + scol]);
      } else {
        bf16x8 ua;
        ua[0] = cvt_bf16(a0[s].x); ua[1] = cvt_bf16(a0[s].y);
        ua[2] = cvt_bf16(a0[s].z); ua[3] = cvt_bf16(a0[s].w);
        ua[4] = cvt_bf16(a1[s].x); ua[5] = cvt_bf16(a1[s].y);
        ua[6] = cvt_bf16(a1[s].z); ua[7] = cvt_bf16(a1[s].w);
        *(bf16x8*)&As[(s * 64 + wave * 16 + srow) * 32 + scol] = ua;
      }
      bf16x8 u;
      u[0] = cvt_bf16(b0[s].x); u[1] = cvt_bf16(b0[s].y);
      u[2] = cvt_bf16(b0[s].z); u[3] = cvt_bf16(b0[s].w);
      u[4] = cvt_bf16(b1[s].x); u[5] = cvt_bf16(b1[s].y);
      u[6] = cvt_bf16(b1[s].z); u[7] = cvt_bf16(b1[s].w);
      *(bf16x8*)&Bs[(s * 64 + wave * 16 + srow) * 32 + scol] = u;
    }
    __syncthreads();

    bf16x8 af[4], bfr[4];
#pragma unroll
    for (int i = 0; i < 4; ++i)
      af[i] = *(const bf16x8*)&As[(wm + i * 16 + (lane & 15)) * 32 + (lane >> 4) * 8];
#pragma unroll
    for (int j = 0; j < 4; ++j)
      bfr[j] = *(const bf16x8*)&Bs[(wn + j * 16 + (lane & 15)) * 32 + (lane >> 4) * 8];

#pragma unroll
    for (int i = 0; i < 4; ++i)
#pragma unroll
      for (int j = 0; j < 4; ++j)
        acc[i][j] = __builtin_amdgcn_mfma_f32_16x16x32_bf16(af[i], bfr[j], acc[i][j], 0, 0, 0);
  }

  // C/D layout (m89-verified): col = lane&15, row = (lane>>4)*4 + reg
#pragma unroll
  for (int i = 0; i < 4; ++i) {
#pragma unroll
    for (int j = 0; j < 4; ++j) {
#pragma unroll
      for (int r = 0; r < 4; ++r) {
        int gm = tile_m + wm + i * 16 + (lane >> 4) * 4 + r;
        int gn = tile_n + wn + j * 16 + (lane & 15);
        if (gn < N) {
          float val = acc[i][j][r];
          if (MODE == 3 || MODE == 5) {
            float bv = bias ? bias[gn] : 0.f;
            val = 1.f / (1.f + __expf(-(val + bv)));
          }
          if (MODE == 4)      Cf[(size_t)gm * N + gn] = val;
          else if (MODE == 5) Cf[(size_t)gn * M + gm] = val;   // transposed
          else                Cb[(size_t)gm * N + gn] = (bf16)val;
        }
      }
    }
  }
}

// Fused 4-projection GEMM: C4 = A @ [Wq;Wk;Wv;Wa]^T, logical N=4096.
// Output: 4 contiguous bf16 planes at C4 (plane = gn>>10). Plane 3 (Wa):
// sigmoid(val + ba[col]). Grid (32,32) = 1024 blocks = 4/CU.
__global__ __launch_bounds__(256) void mega_gemm(
    const bf16* __restrict__ Av, const float* __restrict__ Wq,
    const float* __restrict__ Wk, const float* __restrict__ Wv,
    const float* __restrict__ Wa, const float* __restrict__ ba,
    bf16* __restrict__ C4, int M, int K)
{
  __shared__ __align__(16) __bf16 As[128 * 32];
  __shared__ __align__(16) __bf16 Bs[128 * 32];

  const int tid  = threadIdx.x;
  const int lane = tid & 63;
  const int wave = tid >> 6;
  const int tile_m = blockIdx.y * 128;
  const int tile_n = blockIdx.x * 128;
  const int grp = tile_n >> 10;                 // which weight (tile fully inside)
  const int tnl = tile_n & 1023;                // local col base
  const float* Bt = (grp == 0) ? Wq : (grp == 1) ? Wk : (grp == 2) ? Wv : Wa;
  const int wm = (wave >> 1) * 64;
  const int wn = (wave & 1) * 64;

  const int srow = lane >> 2;
  const int scol = (lane & 3) * 8;

  f32x4 acc[4][4];
#pragma unroll
  for (int i = 0; i < 4; ++i)
#pragma unroll
    for (int j = 0; j < 4; ++j) acc[i][j] = {0.f, 0.f, 0.f, 0.f};

  for (int k0 = 0; k0 < K; k0 += 32) {
    float4 b0[2], b1[2];
#pragma unroll
    for (int s = 0; s < 2; ++s) {
      int brow = tnl + s * 64 + wave * 16 + srow;
      const float* bp = Bt + (size_t)brow * K + k0 + scol;
      b0[s] = *(const float4*)bp;
      b1[s] = *(const float4*)(bp + 4);
    }
    __syncthreads();
#pragma unroll
    for (int s = 0; s < 2; ++s) {
      int arow = tile_m + s * 64 + wave * 16 + srow;
      async_copy16((const __bf16*)Av + (size_t)arow * K + k0 + scol,
                   &As[(s * 64 + wave * 16 + srow) * 32 + scol]);
      bf16x8 u;
      u[0] = cvt_bf16(b0[s].x); u[1] = cvt_bf16(b0[s].y);
      u[2] = cvt_bf16(b0[s].z); u[3] = cvt_bf16(b0[s].w);
      u[4] = cvt_bf16(b1[s].x); u[5] = cvt_bf16(b1[s].y);
      u[6] = cvt_bf16(b1[s].z); u[7] = cvt_bf16(b1[s].w);
      *(bf16x8*)&Bs[(s * 64 + wave * 16 + srow) * 32 + scol] = u;
    }
    __syncthreads();

    bf16x8 af[4], bfr[4];
#pragma unroll
    for (int i = 0; i < 4; ++i)
      af[i] = *(const bf16x8*)&As[(wm + i * 16 + (lane & 15)) * 32 + (lane >> 4) * 8];
#pragma unroll
    for (int j = 0; j < 4; ++j)
      bfr[j] = *(const bf16x8*)&Bs[(wn + j * 16 + (lane & 15)) * 32 + (lane >> 4) * 8];

#pragma unroll
    for (int i = 0; i < 4; ++i)
#pragma unroll
      for (int j = 0; j < 4; ++j)
        acc[i][j] = __builtin_amdgcn_mfma_f32_16x16x32_bf16(af[i], bfr[j], acc[i][j], 0, 0, 0);
  }

  bf16* Cp = (bf16*)((__bf16*)C4 + (size_t)grp * M * 1024);
#pragma unroll
  for (int i = 0; i < 4; ++i) {
#pragma unroll
    for (int j = 0; j < 4; ++j) {
#pragma unroll
      for (int r = 0; r < 4; ++r) {
        int gm = tile_m + wm + i * 16 + (lane >> 4) * 4 + r;
        int col = tnl + wn + j * 16 + (lane & 15);
        float val = acc[i][j][r];
        if (grp == 3) val = 1.f / (1.f + __expf(-(val + ba[col])));
        ((__bf16*)Cp)[(size_t)gm * 1024 + col] = cvt_bf16(val);
      }
    }
  }
}

// causal depthwise conv K=4 + bias + SiLU (+scale), x8 vectorized.
// z: [B*T,1024] bf16 plane; thread handles 8 consecutive channels of 1 row.
__global__ __launch_bounds__(256) void conv_silu_kernel(
    const bf16* __restrict__ z, const float* __restrict__ w,
    const float* __restrict__ bias, bf16* __restrict__ out, float scale)
{
  int idx = blockIdx.x * 256 + threadIdx.x;   // 512K threads
  int c8 = idx & 127;
  int m  = idx >> 7;
  int t  = m & 2047;
  int c0 = c8 * 8;

  const __bf16* base = (const __bf16*)z + (size_t)m * 1024 + c0;
  const bf16x8 zzero = __builtin_bit_cast(bf16x8, (u32x4){0u, 0u, 0u, 0u});
  bf16x8 z3 = *(const bf16x8*)base;
  bf16x8 z2 = (t >= 1) ? *(const bf16x8*)(base - 1024) : zzero;
  bf16x8 z1 = (t >= 2) ? *(const bf16x8*)(base - 2048) : zzero;
  bf16x8 z0 = (t >= 3) ? *(const bf16x8*)(base - 3072) : zzero;

  const float* wp = w + c0 * 4;     // [ch][tap], 32 contiguous floats
  bf16x8 res;
#pragma unroll
  for (int e = 0; e < 8; ++e) {
    float4 we = *(const float4*)(wp + e * 4);
    float acc = bias[c0 + e] + (float)z3[e] * we.w;
    acc += (float)z2[e] * we.z;
    acc += (float)z1[e] * we.y;
    acc += (float)z0[e] * we.x;
    float s = acc / (1.f + __expf(-acc));
    res[e] = cvt_bf16(s * scale);
  }
  *(bf16x8*)((__bf16*)out + (size_t)m * 1024 + c0) = res;
}

// G[h][b*2048+t] = beta[h][b*2048+t] * (k_{t-1} . k_t) over DK=64 (0 at t=0).
__global__ __launch_bounds__(256) void kk_kernel(
    const bf16* __restrict__ k, const float* __restrict__ betab,
    float* __restrict__ G)
{
  int tid = blockIdx.x * 256 + threadIdx.x;
  int out = tid >> 2;            // h*4096 + m, m = b*2048+t
  int j   = tid & 3;
  int h = out >> 12;
  int m = out & 4095;
  int t = m & 2047;
  float s = 0.f;
  if (t > 0) {
    const __bf16* r1 = (const __bf16*)k + (size_t)m * 1024 + h * 64 + j * 16;
    const __bf16* r0 = r1 - 1024;
    bf16x8 a0 = *(const bf16x8*)r0;
    bf16x8 a1 = *(const bf16x8*)(r0 + 8);
    bf16x8 b0 = *(const bf16x8*)r1;
    bf16x8 b1 = *(const bf16x8*)(r1 + 8);
#pragma unroll
    for (int e = 0; e < 8; ++e)
      s += (float)a0[e] * (float)b0[e] + (float)a1[e] * (float)b1[e];
  }
  s += __shfl_xor(s, 1);
  s += __shfl_xor(s, 2);
  if (j == 0) G[out] = betab[out] * s;
}

// One scan step; all operand words are NAMED-variable elements with constant
// indices (no arrays anywhere -> mem2reg promotes -> asm pin is binding).
#define SCAN_STEP(i, KN0, KN1, Q0, Q1, WV, WA, BT, GT, LAST)                  \
  {                                                                           \
    const float vr = ((i) & 1) ? bcf((WV) & 0xffff0000u) : bcf((WV) << 16);   \
    const float ar = ((i) & 1) ? bcf((WA) & 0xffff0000u) : bcf((WA) << 16);   \
    float unxt = 0.f;                                                         \
    f32x2 k2n0 = {0.f, 0.f}, k2n1 = {0.f, 0.f};                               \
    if (!(LAST)) {                                                            \
      k2n0 = unpk(KN0); k2n1 = unpk(KN1);                                     \
      f32x2 dd = S20 * k2n0; dd += S21 * k2n1;                                \
      unxt = dd[0] + dd[1];                                                   \
      unxt += dpp_f<0xB1>(unxt);  unxt += dpp_f<0x4E>(unxt);                  \
      unxt += dpp_f<0x141>(unxt); unxt += dpp_f<0x140>(unxt);                 \
    } else { Sold0 = S20; Sold1 = S21; }                                      \
    float A_ = (BT) * __builtin_fmaf(aprev, u, -vr);                          \
    cc = __builtin_fmaf(-cc, (GT), A_);                                       \
    f32x2 q20 = unpk(Q0), q21 = unpk(Q1);                                     \
    const f32x2 cc2 = {cc, cc}, arv = {ar, ar};                               \
    f32x2 oo;                                                                 \
    { f32x2 t0 = cc2 * k2c0; S20 = arv * S20 - t0; oo = S20 * q20;            \
      f32x2 t1 = cc2 * k2c1; S21 = arv * S21 - t1; oo += S21 * q21; }         \
    so[(i)][lane] = oo[0] + oo[1];                                            \
    aprev = ar;                                                               \
    if (!(LAST)) { k2c0 = k2n0; k2c1 = k2n1; u = unxt; }                      \
  }

// delta-rule scan: look-ahead + chunk-bulk NAMED register operands + asm pin.
// 512 blocks (b,h,qd) x 64 thr; block owns DV rows [qd*4, qd*4+4).
__global__ __launch_bounds__(64, 1) void scan_kernel(
    const bf16* __restrict__ q, const bf16* __restrict__ k,
    const bf16* __restrict__ v, const bf16* __restrict__ a,
    const float* __restrict__ betab, const float* __restrict__ gkk,
    bf16* __restrict__ o)
{
  const int blk = blockIdx.x;
  const int qd = blk >> 5;           // DV slice 0..15 (4 rows each)
  const int bh = blk & 31;
  const int b = bh >> 4, h = bh & 15;
  const int lane = threadIdx.x;      // single wave
  const int r4 = lane >> 4;          // local row 0..3
  const int sg = lane & 15;

  __shared__ __align__(16) __bf16 skT[2][16][72];    // 4608 B
  __shared__ __align__(16) __bf16 sqT[2][16][72];    // 4608 B
  __shared__ __align__(16) __bf16 svaT[2][2][4][16]; // 512 B
  __shared__ __align__(16) float  so[16][68];        // 4352 B
  __shared__ __align__(16) __bf16 so2[16][4];
  __shared__ float sbeta[2048];                      // 8 KB
  __shared__ float sG[2048];                         // 8 KB

  {
    const float* bp = betab + (size_t)h * 4096 + b * 2048;
    const float* gp = gkk   + (size_t)h * 4096 + b * 2048;
    for (int t = lane; t < 2048; t += 64) { sbeta[t] = bp[t]; sG[t] = gp[t]; }
  }

  const size_t bkq = (size_t)b * 2048 * 1024 + h * 64;   // k/q plane base
  const size_t bva = bkq + qd * 4;                       // v/a/o slice base
  const __bf16* kp = (const __bf16*)k;
  const __bf16* qp = (const __bf16*)q;

  const int g_st = lane >> 3;          // staging step-in-group 0..7
  const int g_cg = (lane & 7) * 8;     // staging col (bf16 units)
  const int sgp  = (lane & 7) * 2;     // sg-slice pair base for commit
  const int va_vh = (lane >> 4) & 1;   // lanes 0-15: v, 16-31: a
  const int va_st = lane & 15;

  bf16x8 pk0, pk1, pq0, pq1;
  bf16x4v pva;
  auto fetch = [&](int t0) {
    int st0 = t0 + g_st, st1 = t0 + 8 + g_st;
    pk0 = *(const bf16x8*)(kp + bkq + (size_t)st0 * 1024 + g_cg);
    pk1 = *(const bf16x8*)(kp + bkq + (size_t)st1 * 1024 + g_cg);
    pq0 = *(const bf16x8*)(qp + bkq + (size_t)st0 * 1024 + g_cg);
    pq1 = *(const bf16x8*)(qp + bkq + (size_t)st1 * 1024 + g_cg);
    if (lane < 32) {
      const __bf16* src = va_vh ? (const __bf16*)a : (const __bf16*)v;
      pva = *(const bf16x4v*)(src + bva + (size_t)(t0 + va_st) * 1024);
    }
  };
  auto commit = [&](int cb) {
    {
      u32x4 wk = __builtin_bit_cast(u32x4, pk0);
      u32x4 wq = __builtin_bit_cast(u32x4, pq0);
      u32x2 lo, hi;
      lo[0] = wk[0]; lo[1] = wk[1]; hi[0] = wk[2]; hi[1] = wk[3];
      *(u32x2*)&skT[cb][sgp][g_st * 4]     = lo;
      *(u32x2*)&skT[cb][sgp + 1][g_st * 4] = hi;
      lo[0] = wq[0]; lo[1] = wq[1]; hi[0] = wq[2]; hi[1] = wq[3];
      *(u32x2*)&sqT[cb][sgp][g_st * 4]     = lo;
      *(u32x2*)&sqT[cb][sgp + 1][g_st * 4] = hi;
    }
    {
      u32x4 wk = __builtin_bit_cast(u32x4, pk1);
      u32x4 wq = __builtin_bit_cast(u32x4, pq1);
      u32x2 lo, hi;
      lo[0] = wk[0]; lo[1] = wk[1]; hi[0] = wk[2]; hi[1] = wk[3];
      *(u32x2*)&skT[cb][sgp][(8 + g_st) * 4]     = lo;
      *(u32x2*)&skT[cb][sgp + 1][(8 + g_st) * 4] = hi;
      lo[0] = wq[0]; lo[1] = wq[1]; hi[0] = wq[2]; hi[1] = wq[3];
      *(u32x2*)&sqT[cb][sgp][(8 + g_st) * 4]     = lo;
      *(u32x2*)&sqT[cb][sgp + 1][(8 + g_st) * 4] = hi;
    }
    if (lane < 32) {
#pragma unroll
      for (int r = 0; r < 4; ++r) svaT[cb][va_vh][r][va_st] = pva[r];
    }
  };

  fetch(0); commit(0);

  f32x2 S20 = {0.f, 0.f}, S21 = {0.f, 0.f};
  f32x2 Sold0 = {0.f, 0.f}, Sold1 = {0.f, 0.f};
  float u = 0.f, cc = 0.f, aprev = 0.f;
  __syncthreads();

  auto unpk = [&](unsigned int w) -> f32x2 {
    f32x2 r; r[0] = bcf(w << 16); r[1] = bcf(w & 0xffff0000u); return r;
  };

  for (int c = 0; c < 128; ++c) {
    const int buf = c & 1;
    const bool hasNext = (c + 1 < 128);

    if (hasNext) fetch((c + 1) * 16);   // VMEM issued before the lgkm wait

    // ---- bulk LDS -> NAMED regs: one wait per chunk ----
    u32x4 kw0 = *(const u32x4*)&skT[buf][sg][0];
    u32x4 kw1 = *(const u32x4*)&skT[buf][sg][8];
    u32x4 kw2 = *(const u32x4*)&skT[buf][sg][16];
    u32x4 kw3 = *(const u32x4*)&skT[buf][sg][24];
    u32x4 kw4 = *(const u32x4*)&skT[buf][sg][32];
    u32x4 kw5 = *(const u32x4*)&skT[buf][sg][40];
    u32x4 kw6 = *(const u32x4*)&skT[buf][sg][48];
    u32x4 kw7 = *(const u32x4*)&skT[buf][sg][56];
    u32x4 qw0 = *(const u32x4*)&sqT[buf][sg][0];
    u32x4 qw1 = *(const u32x4*)&sqT[buf][sg][8];
    u32x4 qw2 = *(const u32x4*)&sqT[buf][sg][16];
    u32x4 qw3 = *(const u32x4*)&sqT[buf][sg][24];
    u32x4 qw4 = *(const u32x4*)&sqT[buf][sg][32];
    u32x4 qw5 = *(const u32x4*)&sqT[buf][sg][40];
    u32x4 qw6 = *(const u32x4*)&sqT[buf][sg][48];
    u32x4 qw7 = *(const u32x4*)&sqT[buf][sg][56];
    u32x4 vw0 = *(const u32x4*)&svaT[buf][0][r4][0];
    u32x4 vw1 = *(const u32x4*)&svaT[buf][0][r4][8];
    u32x4 aw0 = *(const u32x4*)&svaT[buf][1][r4][0];
    u32x4 aw1 = *(const u32x4*)&svaT[buf][1][r4][8];
    f32x4 bw0 = *(const f32x4*)&sbeta[c * 16 + 0];
    f32x4 bw1 = *(const f32x4*)&sbeta[c * 16 + 4];
    f32x4 bw2 = *(const f32x4*)&sbeta[c * 16 + 8];
    f32x4 bw3 = *(const f32x4*)&sbeta[c * 16 + 12];
    f32x4 gw0 = *(const f32x4*)&sG[c * 16 + 0];
    f32x4 gw1 = *(const f32x4*)&sG[c * 16 + 4];
    f32x4 gw2 = *(const f32x4*)&sG[c * 16 + 8];
    f32x4 gw3 = *(const f32x4*)&sG[c * 16 + 12];

    // Binding pin: values become asm outputs -> must be materialized here and
    // consumed from registers below (re-load from LDS would be illegal).
    asm volatile("" : "+v"(kw0), "+v"(kw1), "+v"(kw2), "+v"(kw3),
                      "+v"(kw4), "+v"(kw5), "+v"(kw6), "+v"(kw7),
                      "+v"(qw0), "+v"(qw1), "+v"(qw2), "+v"(qw3),
                      "+v"(qw4), "+v"(qw5), "+v"(qw6), "+v"(qw7));
    asm volatile("" : "+v"(vw0), "+v"(vw1), "+v"(aw0), "+v"(aw1),
                      "+v"(bw0), "+v"(bw1), "+v"(bw2), "+v"(bw3),
                      "+v"(gw0), "+v"(gw1), "+v"(gw2), "+v"(gw3));

    // ---- chunk preamble: u for step 0 = Sold . k_0 ----
    f32x2 k2c0 = unpk(kw0[0]);
    f32x2 k2c1 = unpk(kw0[1]);
    {
      f32x2 dd = Sold0 * k2c0;
      dd += Sold1 * k2c1;
      float un = dd[0] + dd[1];
      un += dpp_f<0xB1>(un);
      un += dpp_f<0x4E>(un);
      un += dpp_f<0x141>(un);
      un += dpp_f<0x140>(un);
      u = un;   // c==0: Sold=0 -> u=0, correct
    }

    SCAN_STEP(0,  kw0[2], kw0[3], qw0[0], qw0[1], vw0[0], aw0[0], bw0[0], gw0[0], false)
    SCAN_STEP(1,  kw1[0], kw1[1], qw0[2], qw0[3], vw0[0], aw0[0], bw0[1], gw0[1], false)
    SCAN_STEP(2,  kw1[2], kw1[3], qw1[0], qw1[1], vw0[1], aw0[1], bw0[2], gw0[2], false)
    SCAN_STEP(3,  kw2[0], kw2[1], qw1[2], qw1[3], vw0[1], aw0[1], bw0[3], gw0[3], false)
    SCAN_STEP(4,  kw2[2], kw2[3], qw2[0], qw2[1], vw0[2], aw0[2], bw1[0], gw1[0], false)
    SCAN_STEP(5,  kw3[0], kw3[1], qw2[2], qw2[3], vw0[2], aw0[2], bw1[1], gw1[1], false)
    SCAN_STEP(6,  kw3[2], kw3[3], qw3[0], qw3[1], vw0[3], aw0[3], bw1[2], gw1[2], false)
    SCAN_STEP(7,  kw4[0], kw4[1], qw3[2], qw3[3], vw0[3], aw0[3], bw1[3], gw1[3], false)
    SCAN_STEP(8,  kw4[2], kw4[3], qw4[0], qw4[1], vw1[0], aw1[0], bw2[0], gw2[0], false)
    SCAN_STEP(9,  kw5[0], kw5[1], qw4[2], qw4[3], vw1[0], aw1[0], bw2[1], gw2[1], false)
    SCAN_STEP(10, kw5[2], kw5[3], qw5[0], qw5[1], vw1[1], aw1[1], bw2[2], gw2[2], false)
    SCAN_STEP(11, kw6[0], kw6[1], qw5[2], qw5[3], vw1[1], aw1[1], bw2[3], gw2[3], false)
    SCAN_STEP(12, kw6[2], kw6[3], qw6[0], qw6[1], vw1[2], aw1[2], bw3[0], gw3[0], false)
    SCAN_STEP(13, kw7[0], kw7[1], qw6[2], qw6[3], vw1[2], aw1[2], bw3[1], gw3[1], false)
    SCAN_STEP(14, kw7[2], kw7[3], qw7[0], qw7[1], vw1[3], aw1[3], bw3[2], gw3[2], false)
    SCAN_STEP(15, kw7[2], kw7[3], qw7[2], qw7[3], vw1[3], aw1[3], bw3[3], gw3[3], true)

    // deferred output reduction + coalesced store
    {
      int st = lane >> 2, rr = lane & 3;      // 64 outputs: 16 steps x 4 rows
      float4 A0 = *(const float4*)&so[st][rr * 16];
      float4 A1 = *(const float4*)&so[st][rr * 16 + 4];
      float4 A2 = *(const float4*)&so[st][rr * 16 + 8];
      float4 A3 = *(const float4*)&so[st][rr * 16 + 12];
      float s = (((A0.x + A0.y) + (A0.z + A0.w)) + ((A1.x + A1.y) + (A1.z + A1.w)))
              + (((A2.x + A2.y) + (A2.z + A2.w)) + ((A3.x + A3.y) + (A3.z + A3.w)));
      so2[st][rr] = cvt_bf16(s);
    }
    if (lane < 16)
      *(bf16x4v*)((__bf16*)o + bva + (size_t)(c * 16 + lane) * 1024) =
          *(const bf16x4v*)&so2[lane][0];

    if (hasNext) commit(buf ^ 1);
    __syncthreads();
  }
}

// LayerNorm over DV=64 per (b,t,h) row, *ln_w+ln_b, *gate -> bf16
__global__ __launch_bounds__(256) void ln_gate_kernel(
    const bf16* __restrict__ o, const bf16* __restrict__ g,
    const float* __restrict__ lnw, const float* __restrict__ lnb,
    bf16* __restrict__ out)
{
  int row = blockIdx.x * 4 + (threadIdx.x >> 6);
  int lane = threadIdx.x & 63;
  size_t idx = (size_t)row * 64 + lane;
  float xv = (float)o[idx];
  float mu = xv;
#pragma unroll
  for (int s = 1; s < 64; s <<= 1) mu += __shfl_xor(mu, s);
  mu *= (1.f / 64.f);
  float d = xv - mu;
  float vv = d * d;
#pragma unroll
  for (int s = 1; s < 64; s <<= 1) vv += __shfl_xor(vv, s);
  vv *= (1.f / 64.f);
  float y = d * rsqrtf(vv + 1e-5f) * lnw[lane] + lnb[lane];
  y *= (float)g[idx];
  out[idx] = (bf16)y;
}

extern "C" void kernel_launch(void* const* d_in, const int* in_sizes, int n_in,
                              void* d_out, int out_size, void* d_ws, size_t ws_size,
                              hipStream_t stream)
{
  const float* x   = (const float*)d_in[0];
  const float* Wq  = (const float*)d_in[1];
  const float* Wk  = (const float*)d_in[2];
  const float* Wv  = (const float*)d_in[3];
  const float* Wa  = (const float*)d_in[4];
  const float* ba  = (const float*)d_in[5];
  const float* Wb  = (const float*)d_in[6];
  const float* bb  = (const float*)d_in[7];
  const float* Wg  = (const float*)d_in[8];
  const float* Wo  = (const float*)d_in[9];
  const float* qcw = (const float*)d_in[10];
  const float* qcb = (const float*)d_in[11];
  const float* kcw = (const float*)d_in[12];
  const float* kcb = (const float*)d_in[13];
  const float* vcw = (const float*)d_in[14];
  const float* vcb = (const float*)d_in[15];
  const float* lnw = (const float*)d_in[16];
  const float* lnb = (const float*)d_in[17];

  const int M = 4096, HID = 1024;
  const size_t PLANE = (size_t)M * HID;
  const size_t PB = PLANE * sizeof(bf16);          // 8 MB bf16 plane

  char* ws = (char*)d_ws;
  float* outf  = (float*)d_out;
  float* betab = outf;                               // [0,256K)
  float* gkk   = (float*)((char*)d_out + 256 * 1024);// [256K,512K)
  bf16*  ob    = (bf16*)((char*)d_out + 8 * 1024 * 1024); // [8M,16M)

  const bool rich = (ws_size >= 5 * PB + 1024);

  dim3 blk(256);
  dim3 g8(8, 32);
  int nconv = (int)((size_t)M * 128 / 256);          // x8-vectorized conv grid

  if (rich) {
    bf16* P0 = (bf16*)(ws);
    bf16* P1 = (bf16*)(ws + PB);
    bf16* P2 = (bf16*)(ws + 2 * PB);
    bf16* P3 = (bf16*)(ws + 3 * PB);
    bf16* P4 = (bf16*)(ws + 4 * PB);
    bf16* xb = (bf16*)d_out;                         // [0,8M), dead before betab

    cvt_plane_kernel<<<(int)(PLANE / 1024), blk, 0, stream>>>(x, xb);
    // zq->P0, zk->P1, zv->P2, a(sigmoid+ba)->P3
    mega_gemm<<<dim3(32, 32), blk, 0, stream>>>(xb, Wq, Wk, Wv, Wa, ba, P0, M, HID);
    conv_silu_kernel<<<nconv, blk, 0, stream>>>(P0, qcw, qcb, P4, 1.f);     // q->P4
    conv_silu_kernel<<<nconv, blk, 0, stream>>>(P1, kcw, kcb, P0, 0.125f);  // k->P0
    conv_silu_kernel<<<nconv, blk, 0, stream>>>(P2, vcw, vcb, P1, 1.f);     // v->P1
    gemm_bt<3, false><<<g8, blk, 0, stream>>>(xb, Wg, nullptr, nullptr, P2, M, HID, HID); // g->P2
    gemm_bt<5, false><<<dim3(1, 32), blk, 0, stream>>>(xb, Wb, bb, betab, nullptr, M, 16, HID);
    kk_kernel<<<1024, blk, 0, stream>>>(P0, betab, gkk);
    scan_kernel<<<512, dim3(64), 0, stream>>>(P4, P0, P1, P3, betab, gkk, ob);
    ln_gate_kernel<<<M * 16 / 4, blk, 0, stream>>>(ob, P2, lnw, lnb, P3);   // ->P3
    gemm_bt<4, false><<<g8, blk, 0, stream>>>(P3, Wo, nullptr, outf, nullptr, M, HID, HID);
  } else {
    bf16* P  = (bf16*)(ws);
    bf16* qb = (bf16*)(ws + PB);
    bf16* kb = (bf16*)(ws + 2 * PB);
    bf16* vb = (bf16*)(ws + 3 * PB);

    gemm_bt<2, true><<<g8, blk, 0, stream>>>(x, Wq, nullptr, nullptr, P, M, HID, HID);
    conv_silu_kernel<<<nconv, blk, 0, stream>>>(P, qcw, qcb, qb, 1.f);
    gemm_bt<2, true><<<g8, blk, 0, stream>>>(x, Wk, nullptr, nullptr, P, M, HID, HID);
    conv_silu_kernel<<<nconv, blk, 0, stream>>>(P, kcw, kcb, kb, 0.125f);
    gemm_bt<2, true><<<g8, blk, 0, stream>>>(x, Wv, nullptr, nullptr, P, M, HID, HID);
    conv_silu_kernel<<<nconv, blk, 0, stream>>>(P, vcw, vcb, vb, 1.f);
    gemm_bt<3, true><<<g8, blk, 0, stream>>>(x, Wa, ba, nullptr, P, M, HID, HID);
    gemm_bt<5, true><<<dim3(1, 32), blk, 0, stream>>>(x, Wb, bb, betab, nullptr, M, 16, HID);
    kk_kernel<<<1024, blk, 0, stream>>>(kb, betab, gkk);
    scan_kernel<<<512, dim3(64), 0, stream>>>(qb, kb, vb, P, betab, gkk, ob);
    gemm_bt<3, true><<<g8, blk, 0, stream>>>(x, Wg, nullptr, nullptr, qb, M, HID, HID);
    ln_gate_kernel<<<M * 16 / 4, blk, 0, stream>>>(ob, qb, lnw, lnb, kb);
    gemm_bt<4, false><<<g8, blk, 0, stream>>>(kb, Wo, nullptr, outf, nullptr, M, HID, HID);
  }
}

// Round 7
// 551.518 us; speedup vs baseline: 1.0098x; 1.0098x over previous
//
#include <hip/hip_runtime.h>
#include <hip/hip_bf16.h>
#include <cstdint>

// B=2, T=2048, HID=1024, H=16, DK=DV=64, K(conv)=4. fp32 in/out.
// RICH layout (ws >= 40MB): ws = 5 bf16 planes P0..P4 (8 MB each).
//   d_out scratch: xb bf16 [0,8M) (dead after g/beta GEMMs);
//   betab fp32 [16][4096] at [0,256K); G at [256K,512K); ob bf16 at [8M,16M).
// Pipeline: cvt -> mega_gemm(zq,zk,zv,a) -> conv q/k/v (x8) -> g-GEMM
//   -> beta-GEMM -> kk -> scan -> ln_gate -> final GEMM.
//
// Scan: look-ahead transform (serial chain = 1 fma/step).
// R2-R6 lesson: the register allocator holds an ~88-VGPR budget and
// spills/sinks any 112-reg bulk-load schedule (sched_barrier, launch_bounds,
// asm "+v" pins all null). This version pipelines 2-STEP GROUPS with 3 sets
// in flight (A/B/C, 14 regs each): group g+2's LDS loads issue between group
// g's compute -> 4-step prefetch distance (~150 cyc > 120-cyc LDS latency)
// at ~85 live regs, UNDER the allocator's budget.

using bf16 = __hip_bfloat16;
typedef __bf16 bf16x8 __attribute__((ext_vector_type(8)));
typedef __bf16 bf16x4v __attribute__((ext_vector_type(4)));
typedef float f32x4 __attribute__((ext_vector_type(4)));
typedef float f32x2 __attribute__((ext_vector_type(2)));
typedef unsigned int u32x4 __attribute__((ext_vector_type(4)));
typedef unsigned int u32x2 __attribute__((ext_vector_type(2)));

__device__ __forceinline__ __bf16 cvt_bf16(float f) {
  __hip_bfloat16 h = (__hip_bfloat16)f;
  return *reinterpret_cast<__bf16*>(&h);
}
__device__ __forceinline__ void async_copy16(const void* g, void* l) {
  __builtin_amdgcn_global_load_lds((const __attribute__((address_space(1))) void*)g,
                                   (__attribute__((address_space(3))) void*)l,
                                   16, 0, 0);
}
__device__ __forceinline__ float bcf(unsigned int u) { return __builtin_bit_cast(float, u); }
template <int CTRL>
__device__ __forceinline__ float dpp_f(float x) {
  int y = __builtin_amdgcn_update_dpp(0, __builtin_bit_cast(int, x), CTRL, 0xF, 0xF, true);
  return __builtin_bit_cast(float, y);
}

// fp32 -> bf16 plane (4M elements)
__global__ __launch_bounds__(256) void cvt_plane_kernel(
    const float* __restrict__ in, bf16* __restrict__ out)
{
  size_t i = ((size_t)blockIdx.x * 256 + threadIdx.x) * 4;
  float4 f = *(const float4*)(in + i);
  bf16x4v t;
  t[0] = cvt_bf16(f.x); t[1] = cvt_bf16(f.y); t[2] = cvt_bf16(f.z); t[3] = cvt_bf16(f.w);
  *(bf16x4v*)((__bf16*)out + i) = t;
}

// C = A * Bt^T. A: MxK (bf16 async-staged unless A_FP32); Bt: NxK fp32.
// MODE 2: raw->bf16; 3: sigmoid(acc+bias)->bf16; 4: raw->fp32; 5: sigmoid(acc+bias)->fp32 TRANSPOSED
template <int MODE, bool A_FP32>
__global__ __launch_bounds__(256) void gemm_bt(
    const void* __restrict__ Av, const float* __restrict__ Bt,
    const float* __restrict__ bias, float* __restrict__ Cf, bf16* __restrict__ Cb,
    int M, int N, int K)
{
  __shared__ __align__(16) __bf16 As[128 * 32];
  __shared__ __align__(16) __bf16 Bs[128 * 32];

  const int tid  = threadIdx.x;
  const int lane = tid & 63;
  const int wave = tid >> 6;
  const int tile_m = blockIdx.y * 128;
  const int tile_n = blockIdx.x * 128;
  const int wm = (wave >> 1) * 64;
  const int wn = (wave & 1) * 64;

  const int srow = lane >> 2;
  const int scol = (lane & 3) * 8;

  f32x4 acc[4][4];
#pragma unroll
  for (int i = 0; i < 4; ++i)
#pragma unroll
    for (int j = 0; j < 4; ++j) acc[i][j] = {0.f, 0.f, 0.f, 0.f};

  for (int k0 = 0; k0 < K; k0 += 32) {
    float4 b0[2], b1[2], a0[2], a1[2];
#pragma unroll
    for (int s = 0; s < 2; ++s) {
      int brow = tile_n + s * 64 + wave * 16 + srow;
      if (brow > N - 1) brow = N - 1;             // clamp (beta GEMM: N=16)
      const float* bp = Bt + (size_t)brow * K + k0 + scol;
      b0[s] = *(const float4*)bp;
      b1[s] = *(const float4*)(bp + 4);
      if (A_FP32) {
        int arow = tile_m + s * 64 + wave * 16 + srow;
        const float* ap = (const float*)Av + (size_t)arow * K + k0 + scol;
        a0[s] = *(const float4*)ap;
        a1[s] = *(const float4*)(ap + 4);
      }
    }
    __syncthreads();
#pragma unroll
    for (int s = 0; s < 2; ++s) {
      if (!A_FP32) {
        int arow = tile_m + s * 64 + wave * 16 + srow;
        async_copy16((const __bf16*)Av + (size_t)arow * K + k0 + scol,
                     &As[(s * 64 + wave * 16 + srow) * 32 + scol]);
      } else {
        bf16x8 ua;
        ua[0] = cvt_bf16(a0[s].x); ua[1] = cvt_bf16(a0[s].y);
        ua[2] = cvt_bf16(a0[s].z); ua[3] = cvt_bf16(a0[s].w);
        ua[4] = cvt_bf16(a1[s].x); ua[5] = cvt_bf16(a1[s].y);
        ua[6] = cvt_bf16(a1[s].z); ua[7] = cvt_bf16(a1[s].w);
        *(bf16x8*)&As[(s * 64 + wave * 16 + srow) * 32 + scol] = ua;
      }
      bf16x8 u;
      u[0] = cvt_bf16(b0[s].x); u[1] = cvt_bf16(b0[s].y);
      u[2] = cvt_bf16(b0[s].z); u[3] = cvt_bf16(b0[s].w);
      u[4] = cvt_bf16(b1[s].x); u[5] = cvt_bf16(b1[s].y);
      u[6] = cvt_bf16(b1[s].z); u[7] = cvt_bf16(b1[s].w);
      *(bf16x8*)&Bs[(s * 64 + wave * 16 + srow) * 32 + scol] = u;
    }
    __syncthreads();

    bf16x8 af[4], bfr[4];
#pragma unroll
    for (int i = 0; i < 4; ++i)
      af[i] = *(const bf16x8*)&As[(wm + i * 16 + (lane & 15)) * 32 + (lane >> 4) * 8];
#pragma unroll
    for (int j = 0; j < 4; ++j)
      bfr[j] = *(const bf16x8*)&Bs[(wn + j * 16 + (lane & 15)) * 32 + (lane >> 4) * 8];

#pragma unroll
    for (int i = 0; i < 4; ++i)
#pragma unroll
      for (int j = 0; j < 4; ++j)
        acc[i][j] = __builtin_amdgcn_mfma_f32_16x16x32_bf16(af[i], bfr[j], acc[i][j], 0, 0, 0);
  }

  // C/D layout (m89-verified): col = lane&15, row = (lane>>4)*4 + reg
#pragma unroll
  for (int i = 0; i < 4; ++i) {
#pragma unroll
    for (int j = 0; j < 4; ++j) {
#pragma unroll
      for (int r = 0; r < 4; ++r) {
        int gm = tile_m + wm + i * 16 + (lane >> 4) * 4 + r;
        int gn = tile_n + wn + j * 16 + (lane & 15);
        if (gn < N) {
          float val = acc[i][j][r];
          if (MODE == 3 || MODE == 5) {
            float bv = bias ? bias[gn] : 0.f;
            val = 1.f / (1.f + __expf(-(val + bv)));
          }
          if (MODE == 4)      Cf[(size_t)gm * N + gn] = val;
          else if (MODE == 5) Cf[(size_t)gn * M + gm] = val;   // transposed
          else                Cb[(size_t)gm * N + gn] = (bf16)val;
        }
      }
    }
  }
}

// Fused 4-projection GEMM: C4 = A @ [Wq;Wk;Wv;Wa]^T, logical N=4096.
__global__ __launch_bounds__(256) void mega_gemm(
    const bf16* __restrict__ Av, const float* __restrict__ Wq,
    const float* __restrict__ Wk, const float* __restrict__ Wv,
    const float* __restrict__ Wa, const float* __restrict__ ba,
    bf16* __restrict__ C4, int M, int K)
{
  __shared__ __align__(16) __bf16 As[128 * 32];
  __shared__ __align__(16) __bf16 Bs[128 * 32];

  const int tid  = threadIdx.x;
  const int lane = tid & 63;
  const int wave = tid >> 6;
  const int tile_m = blockIdx.y * 128;
  const int tile_n = blockIdx.x * 128;
  const int grp = tile_n >> 10;                 // which weight (tile fully inside)
  const int tnl = tile_n & 1023;                // local col base
  const float* Bt = (grp == 0) ? Wq : (grp == 1) ? Wk : (grp == 2) ? Wv : Wa;
  const int wm = (wave >> 1) * 64;
  const int wn = (wave & 1) * 64;

  const int srow = lane >> 2;
  const int scol = (lane & 3) * 8;

  f32x4 acc[4][4];
#pragma unroll
  for (int i = 0; i < 4; ++i)
#pragma unroll
    for (int j = 0; j < 4; ++j) acc[i][j] = {0.f, 0.f, 0.f, 0.f};

  for (int k0 = 0; k0 < K; k0 += 32) {
    float4 b0[2], b1[2];
#pragma unroll
    for (int s = 0; s < 2; ++s) {
      int brow = tnl + s * 64 + wave * 16 + srow;
      const float* bp = Bt + (size_t)brow * K + k0 + scol;
      b0[s] = *(const float4*)bp;
      b1[s] = *(const float4*)(bp + 4);
    }
    __syncthreads();
#pragma unroll
    for (int s = 0; s < 2; ++s) {
      int arow = tile_m + s * 64 + wave * 16 + srow;
      async_copy16((const __bf16*)Av + (size_t)arow * K + k0 + scol,
                   &As[(s * 64 + wave * 16 + srow) * 32 + scol]);
      bf16x8 u;
      u[0] = cvt_bf16(b0[s].x); u[1] = cvt_bf16(b0[s].y);
      u[2] = cvt_bf16(b0[s].z); u[3] = cvt_bf16(b0[s].w);
      u[4] = cvt_bf16(b1[s].x); u[5] = cvt_bf16(b1[s].y);
      u[6] = cvt_bf16(b1[s].z); u[7] = cvt_bf16(b1[s].w);
      *(bf16x8*)&Bs[(s * 64 + wave * 16 + srow) * 32 + scol] = u;
    }
    __syncthreads();

    bf16x8 af[4], bfr[4];
#pragma unroll
    for (int i = 0; i < 4; ++i)
      af[i] = *(const bf16x8*)&As[(wm + i * 16 + (lane & 15)) * 32 + (lane >> 4) * 8];
#pragma unroll
    for (int j = 0; j < 4; ++j)
      bfr[j] = *(const bf16x8*)&Bs[(wn + j * 16 + (lane & 15)) * 32 + (lane >> 4) * 8];

#pragma unroll
    for (int i = 0; i < 4; ++i)
#pragma unroll
      for (int j = 0; j < 4; ++j)
        acc[i][j] = __builtin_amdgcn_mfma_f32_16x16x32_bf16(af[i], bfr[j], acc[i][j], 0, 0, 0);
  }

  bf16* Cp = (bf16*)((__bf16*)C4 + (size_t)grp * M * 1024);
#pragma unroll
  for (int i = 0; i < 4; ++i) {
#pragma unroll
    for (int j = 0; j < 4; ++j) {
#pragma unroll
      for (int r = 0; r < 4; ++r) {
        int gm = tile_m + wm + i * 16 + (lane >> 4) * 4 + r;
        int col = tnl + wn + j * 16 + (lane & 15);
        float val = acc[i][j][r];
        if (grp == 3) val = 1.f / (1.f + __expf(-(val + ba[col])));
        ((__bf16*)Cp)[(size_t)gm * 1024 + col] = cvt_bf16(val);
      }
    }
  }
}

// causal depthwise conv K=4 + bias + SiLU (+scale), x8 vectorized.
__global__ __launch_bounds__(256) void conv_silu_kernel(
    const bf16* __restrict__ z, const float* __restrict__ w,
    const float* __restrict__ bias, bf16* __restrict__ out, float scale)
{
  int idx = blockIdx.x * 256 + threadIdx.x;   // 512K threads
  int c8 = idx & 127;
  int m  = idx >> 7;
  int t  = m & 2047;
  int c0 = c8 * 8;

  const __bf16* base = (const __bf16*)z + (size_t)m * 1024 + c0;
  const bf16x8 zzero = __builtin_bit_cast(bf16x8, (u32x4){0u, 0u, 0u, 0u});
  bf16x8 z3 = *(const bf16x8*)base;
  bf16x8 z2 = (t >= 1) ? *(const bf16x8*)(base - 1024) : zzero;
  bf16x8 z1 = (t >= 2) ? *(const bf16x8*)(base - 2048) : zzero;
  bf16x8 z0 = (t >= 3) ? *(const bf16x8*)(base - 3072) : zzero;

  const float* wp = w + c0 * 4;     // [ch][tap], 32 contiguous floats
  bf16x8 res;
#pragma unroll
  for (int e = 0; e < 8; ++e) {
    float4 we = *(const float4*)(wp + e * 4);
    float acc = bias[c0 + e] + (float)z3[e] * we.w;
    acc += (float)z2[e] * we.z;
    acc += (float)z1[e] * we.y;
    acc += (float)z0[e] * we.x;
    float s = acc / (1.f + __expf(-acc));
    res[e] = cvt_bf16(s * scale);
  }
  *(bf16x8*)((__bf16*)out + (size_t)m * 1024 + c0) = res;
}

// G[h][b*2048+t] = beta[h][b*2048+t] * (k_{t-1} . k_t) over DK=64 (0 at t=0).
__global__ __launch_bounds__(256) void kk_kernel(
    const bf16* __restrict__ k, const float* __restrict__ betab,
    float* __restrict__ G)
{
  int tid = blockIdx.x * 256 + threadIdx.x;
  int out = tid >> 2;            // h*4096 + m, m = b*2048+t
  int j   = tid & 3;
  int h = out >> 12;
  int m = out & 4095;
  int t = m & 2047;
  float s = 0.f;
  if (t > 0) {
    const __bf16* r1 = (const __bf16*)k + (size_t)m * 1024 + h * 64 + j * 16;
    const __bf16* r0 = r1 - 1024;
    bf16x8 a0 = *(const bf16x8*)r0;
    bf16x8 a1 = *(const bf16x8*)(r0 + 8);
    bf16x8 b0 = *(const bf16x8*)r1;
    bf16x8 b1 = *(const bf16x8*)(r1 + 8);
#pragma unroll
    for (int e = 0; e < 8; ++e)
      s += (float)a0[e] * (float)b0[e] + (float)a1[e] * (float)b1[e];
  }
  s += __shfl_xor(s, 1);
  s += __shfl_xor(s, 2);
  if (j == 0) G[out] = betab[out] * s;
}

// One scan step (constant word indices only).
#define SCAN_STEP(i, KN0, KN1, Q0, Q1, WV, WA, BT, GT, LAST)                  \
  {                                                                           \
    const float vr = ((i) & 1) ? bcf((WV) & 0xffff0000u) : bcf((WV) << 16);   \
    const float ar = ((i) & 1) ? bcf((WA) & 0xffff0000u) : bcf((WA) << 16);   \
    float unxt = 0.f;                                                         \
    f32x2 k2n0 = {0.f, 0.f}, k2n1 = {0.f, 0.f};                               \
    if (!(LAST)) {                                                            \
      k2n0 = unpk(KN0); k2n1 = unpk(KN1);                                     \
      f32x2 dd = S20 * k2n0; dd += S21 * k2n1;                                \
      unxt = dd[0] + dd[1];                                                   \
      unxt += dpp_f<0xB1>(unxt);  unxt += dpp_f<0x4E>(unxt);                  \
      unxt += dpp_f<0x141>(unxt); unxt += dpp_f<0x140>(unxt);                 \
    } else { Sold0 = S20; Sold1 = S21; }                                      \
    float A_ = (BT) * __builtin_fmaf(aprev, u, -vr);                          \
    cc = __builtin_fmaf(-cc, (GT), A_);                                       \
    f32x2 q20 = unpk(Q0), q21 = unpk(Q1);                                     \
    const f32x2 cc2 = {cc, cc}, arv = {ar, ar};                               \
    f32x2 oo;                                                                 \
    { f32x2 t0 = cc2 * k2c0; S20 = arv * S20 - t0; oo = S20 * q20;            \
      f32x2 t1 = cc2 * k2c1; S21 = arv * S21 - t1; oo += S21 * q21; }         \
    so[(i)][lane] = oo[0] + oo[1];                                            \
    aprev = ar;                                                               \
    if (!(LAST)) { k2c0 = k2n0; k2c1 = k2n1; u = unxt; }                      \
  }

// Load one 2-step group (g = 0..7) into a named set (14 regs).
#define LOADG(KS, QS, VS, AS, BS, GS, g)                                      \
  KS = *(const u32x4*)&skT[buf][sg][(g) * 8];                                 \
  QS = *(const u32x4*)&sqT[buf][sg][(g) * 8];                                 \
  VS = *(const unsigned int*)&svaT[buf][0][r4][(g) * 2];                      \
  AS = *(const unsigned int*)&svaT[buf][1][r4][(g) * 2];                      \
  BS = *(const f32x2*)&sbeta[c * 16 + (g) * 2];                               \
  GS = *(const f32x2*)&sG[c * 16 + (g) * 2];

// delta-rule scan: look-ahead + 2-step-group pipeline (3 sets in flight).
// 512 blocks (b,h,qd) x 64 thr; block owns DV rows [qd*4, qd*4+4).
__global__ __launch_bounds__(64, 1) void scan_kernel(
    const bf16* __restrict__ q, const bf16* __restrict__ k,
    const bf16* __restrict__ v, const bf16* __restrict__ a,
    const float* __restrict__ betab, const float* __restrict__ gkk,
    bf16* __restrict__ o)
{
  const int blk = blockIdx.x;
  const int qd = blk >> 5;           // DV slice 0..15 (4 rows each)
  const int bh = blk & 31;
  const int b = bh >> 4, h = bh & 15;
  const int lane = threadIdx.x;      // single wave
  const int r4 = lane >> 4;          // local row 0..3
  const int sg = lane & 15;

  __shared__ __align__(16) __bf16 skT[2][16][72];    // 4608 B
  __shared__ __align__(16) __bf16 sqT[2][16][72];    // 4608 B
  __shared__ __align__(16) __bf16 svaT[2][2][4][16]; // 512 B
  __shared__ __align__(16) float  so[16][68];        // 4352 B
  __shared__ __align__(16) __bf16 so2[16][4];
  __shared__ float sbeta[2048];                      // 8 KB
  __shared__ float sG[2048];                         // 8 KB

  {
    const float* bp = betab + (size_t)h * 4096 + b * 2048;
    const float* gp = gkk   + (size_t)h * 4096 + b * 2048;
    for (int t = lane; t < 2048; t += 64) { sbeta[t] = bp[t]; sG[t] = gp[t]; }
  }

  const size_t bkq = (size_t)b * 2048 * 1024 + h * 64;   // k/q plane base
  const size_t bva = bkq + qd * 4;                       // v/a/o slice base
  const __bf16* kp = (const __bf16*)k;
  const __bf16* qp = (const __bf16*)q;

  const int g_st = lane >> 3;          // staging step-in-group 0..7
  const int g_cg = (lane & 7) * 8;     // staging col (bf16 units)
  const int sgp  = (lane & 7) * 2;     // sg-slice pair base for commit
  const int va_vh = (lane >> 4) & 1;   // lanes 0-15: v, 16-31: a
  const int va_st = lane & 15;

  bf16x8 pk0, pk1, pq0, pq1;
  bf16x4v pva;
  auto fetch = [&](int t0) {
    int st0 = t0 + g_st, st1 = t0 + 8 + g_st;
    pk0 = *(const bf16x8*)(kp + bkq + (size_t)st0 * 1024 + g_cg);
    pk1 = *(const bf16x8*)(kp + bkq + (size_t)st1 * 1024 + g_cg);
    pq0 = *(const bf16x8*)(qp + bkq + (size_t)st0 * 1024 + g_cg);
    pq1 = *(const bf16x8*)(qp + bkq + (size_t)st1 * 1024 + g_cg);
    if (lane < 32) {
      const __bf16* src = va_vh ? (const __bf16*)a : (const __bf16*)v;
      pva = *(const bf16x4v*)(src + bva + (size_t)(t0 + va_st) * 1024);
    }
  };
  auto commit = [&](int cb) {
    {
      u32x4 wk = __builtin_bit_cast(u32x4, pk0);
      u32x4 wq = __builtin_bit_cast(u32x4, pq0);
      u32x2 lo, hi;
      lo[0] = wk[0]; lo[1] = wk[1]; hi[0] = wk[2]; hi[1] = wk[3];
      *(u32x2*)&skT[cb][sgp][g_st * 4]     = lo;
      *(u32x2*)&skT[cb][sgp + 1][g_st * 4] = hi;
      lo[0] = wq[0]; lo[1] = wq[1]; hi[0] = wq[2]; hi[1] = wq[3];
      *(u32x2*)&sqT[cb][sgp][g_st * 4]     = lo;
      *(u32x2*)&sqT[cb][sgp + 1][g_st * 4] = hi;
    }
    {
      u32x4 wk = __builtin_bit_cast(u32x4, pk1);
      u32x4 wq = __builtin_bit_cast(u32x4, pq1);
      u32x2 lo, hi;
      lo[0] = wk[0]; lo[1] = wk[1]; hi[0] = wk[2]; hi[1] = wk[3];
      *(u32x2*)&skT[cb][sgp][(8 + g_st) * 4]     = lo;
      *(u32x2*)&skT[cb][sgp + 1][(8 + g_st) * 4] = hi;
      lo[0] = wq[0]; lo[1] = wq[1]; hi[0] = wq[2]; hi[1] = wq[3];
      *(u32x2*)&sqT[cb][sgp][(8 + g_st) * 4]     = lo;
      *(u32x2*)&sqT[cb][sgp + 1][(8 + g_st) * 4] = hi;
    }
    if (lane < 32) {
#pragma unroll
      for (int r = 0; r < 4; ++r) svaT[cb][va_vh][r][va_st] = pva[r];
    }
  };

  fetch(0); commit(0);

  f32x2 S20 = {0.f, 0.f}, S21 = {0.f, 0.f};
  f32x2 Sold0 = {0.f, 0.f}, Sold1 = {0.f, 0.f};
  float u = 0.f, cc = 0.f, aprev = 0.f;
  __syncthreads();

  auto unpk = [&](unsigned int w) -> f32x2 {
    f32x2 r; r[0] = bcf(w << 16); r[1] = bcf(w & 0xffff0000u); return r;
  };

  for (int c = 0; c < 128; ++c) {
    const int buf = c & 1;
    const bool hasNext = (c + 1 < 128);

    if (hasNext) fetch((c + 1) * 16);   // VMEM issued first

    // ---- 3-set pipeline over eight 2-step groups ----
    u32x4 kA, qA, kB, qB, kC, qC;
    unsigned int vA, aA, vB, aB, vC, aC;
    f32x2 bA, gA, bB, gB, bC, gC;

    LOADG(kA, qA, vA, aA, bA, gA, 0)
    LOADG(kB, qB, vB, aB, bB, gB, 1)
    LOADG(kC, qC, vC, aC, bC, gC, 2)

    // chunk preamble: u for step 0 = Sold . k_0
    f32x2 k2c0 = unpk(kA[0]);
    f32x2 k2c1 = unpk(kA[1]);
    {
      f32x2 dd = Sold0 * k2c0;
      dd += Sold1 * k2c1;
      float un = dd[0] + dd[1];
      un += dpp_f<0xB1>(un);
      un += dpp_f<0x4E>(un);
      un += dpp_f<0x141>(un);
      un += dpp_f<0x140>(un);
      u = un;   // c==0: Sold=0 -> u=0, correct
    }

    SCAN_STEP(0,  kA[2], kA[3], qA[0], qA[1], vA, aA, bA[0], gA[0], false)
    SCAN_STEP(1,  kB[0], kB[1], qA[2], qA[3], vA, aA, bA[1], gA[1], false)
    LOADG(kA, qA, vA, aA, bA, gA, 3)
    SCAN_STEP(2,  kB[2], kB[3], qB[0], qB[1], vB, aB, bB[0], gB[0], false)
    SCAN_STEP(3,  kC[0], kC[1], qB[2], qB[3], vB, aB, bB[1], gB[1], false)
    LOADG(kB, qB, vB, aB, bB, gB, 4)
    SCAN_STEP(4,  kC[2], kC[3], qC[0], qC[1], vC, aC, bC[0], gC[0], false)
    SCAN_STEP(5,  kA[0], kA[1], qC[2], qC[3], vC, aC, bC[1], gC[1], false)  // kA = g3
    LOADG(kC, qC, vC, aC, bC, gC, 5)
    SCAN_STEP(6,  kA[2], kA[3], qA[0], qA[1], vA, aA, bA[0], gA[0], false)  // g3
    SCAN_STEP(7,  kB[0], kB[1], qA[2], qA[3], vA, aA, bA[1], gA[1], false)  // kB = g4
    LOADG(kA, qA, vA, aA, bA, gA, 6)
    SCAN_STEP(8,  kB[2], kB[3], qB[0], qB[1], vB, aB, bB[0], gB[0], false)  // g4
    SCAN_STEP(9,  kC[0], kC[1], qB[2], qB[3], vB, aB, bB[1], gB[1], false)  // kC = g5
    LOADG(kB, qB, vB, aB, bB, gB, 7)
    SCAN_STEP(10, kC[2], kC[3], qC[0], qC[1], vC, aC, bC[0], gC[0], false)  // g5
    SCAN_STEP(11, kA[0], kA[1], qC[2], qC[3], vC, aC, bC[1], gC[1], false)  // kA = g6
    SCAN_STEP(12, kA[2], kA[3], qA[0], qA[1], vA, aA, bA[0], gA[0], false)  // g6
    SCAN_STEP(13, kB[0], kB[1], qA[2], qA[3], vA, aA, bA[1], gA[1], false)  // kB = g7
    SCAN_STEP(14, kB[2], kB[3], qB[0], qB[1], vB, aB, bB[0], gB[0], false)  // g7
    SCAN_STEP(15, kB[2], kB[3], qB[2], qB[3], vB, aB, bB[1], gB[1], true)   // LAST

    // deferred output reduction + coalesced store
    {
      int st = lane >> 2, rr = lane & 3;      // 64 outputs: 16 steps x 4 rows
      float4 A0 = *(const float4*)&so[st][rr * 16];
      float4 A1 = *(const float4*)&so[st][rr * 16 + 4];
      float4 A2 = *(const float4*)&so[st][rr * 16 + 8];
      float4 A3 = *(const float4*)&so[st][rr * 16 + 12];
      float s = (((A0.x + A0.y) + (A0.z + A0.w)) + ((A1.x + A1.y) + (A1.z + A1.w)))
              + (((A2.x + A2.y) + (A2.z + A2.w)) + ((A3.x + A3.y) + (A3.z + A3.w)));
      so2[st][rr] = cvt_bf16(s);
    }
    if (lane < 16)
      *(bf16x4v*)((__bf16*)o + bva + (size_t)(c * 16 + lane) * 1024) =
          *(const bf16x4v*)&so2[lane][0];

    if (hasNext) commit(buf ^ 1);
    __syncthreads();
  }
}

// LayerNorm over DV=64 per (b,t,h) row, *ln_w+ln_b, *gate -> bf16
__global__ __launch_bounds__(256) void ln_gate_kernel(
    const bf16* __restrict__ o, const bf16* __restrict__ g,
    const float* __restrict__ lnw, const float* __restrict__ lnb,
    bf16* __restrict__ out)
{
  int row = blockIdx.x * 4 + (threadIdx.x >> 6);
  int lane = threadIdx.x & 63;
  size_t idx = (size_t)row * 64 + lane;
  float xv = (float)o[idx];
  float mu = xv;
#pragma unroll
  for (int s = 1; s < 64; s <<= 1) mu += __shfl_xor(mu, s);
  mu *= (1.f / 64.f);
  float d = xv - mu;
  float vv = d * d;
#pragma unroll
  for (int s = 1; s < 64; s <<= 1) vv += __shfl_xor(vv, s);
  vv *= (1.f / 64.f);
  float y = d * rsqrtf(vv + 1e-5f) * lnw[lane] + lnb[lane];
  y *= (float)g[idx];
  out[idx] = (bf16)y;
}

extern "C" void kernel_launch(void* const* d_in, const int* in_sizes, int n_in,
                              void* d_out, int out_size, void* d_ws, size_t ws_size,
                              hipStream_t stream)
{
  const float* x   = (const float*)d_in[0];
  const float* Wq  = (const float*)d_in[1];
  const float* Wk  = (const float*)d_in[2];
  const float* Wv  = (const float*)d_in[3];
  const float* Wa  = (const float*)d_in[4];
  const float* ba  = (const float*)d_in[5];
  const float* Wb  = (const float*)d_in[6];
  const float* bb  = (const float*)d_in[7];
  const float* Wg  = (const float*)d_in[8];
  const float* Wo  = (const float*)d_in[9];
  const float* qcw = (const float*)d_in[10];
  const float* qcb = (const float*)d_in[11];
  const float* kcw = (const float*)d_in[12];
  const float* kcb = (const float*)d_in[13];
  const float* vcw = (const float*)d_in[14];
  const float* vcb = (const float*)d_in[15];
  const float* lnw = (const float*)d_in[16];
  const float* lnb = (const float*)d_in[17];

  const int M = 4096, HID = 1024;
  const size_t PLANE = (size_t)M * HID;
  const size_t PB = PLANE * sizeof(bf16);          // 8 MB bf16 plane

  char* ws = (char*)d_ws;
  float* outf  = (float*)d_out;
  float* betab = outf;                               // [0,256K)
  float* gkk   = (float*)((char*)d_out + 256 * 1024);// [256K,512K)
  bf16*  ob    = (bf16*)((char*)d_out + 8 * 1024 * 1024); // [8M,16M)

  const bool rich = (ws_size >= 5 * PB + 1024);

  dim3 blk(256);
  dim3 g8(8, 32);
  int nconv = (int)((size_t)M * 128 / 256);          // x8-vectorized conv grid

  if (rich) {
    bf16* P0 = (bf16*)(ws);
    bf16* P1 = (bf16*)(ws + PB);
    bf16* P2 = (bf16*)(ws + 2 * PB);
    bf16* P3 = (bf16*)(ws + 3 * PB);
    bf16* P4 = (bf16*)(ws + 4 * PB);
    bf16* xb = (bf16*)d_out;                         // [0,8M), dead before betab

    cvt_plane_kernel<<<(int)(PLANE / 1024), blk, 0, stream>>>(x, xb);
    // zq->P0, zk->P1, zv->P2, a(sigmoid+ba)->P3
    mega_gemm<<<dim3(32, 32), blk, 0, stream>>>(xb, Wq, Wk, Wv, Wa, ba, P0, M, HID);
    conv_silu_kernel<<<nconv, blk, 0, stream>>>(P0, qcw, qcb, P4, 1.f);     // q->P4
    conv_silu_kernel<<<nconv, blk, 0, stream>>>(P1, kcw, kcb, P0, 0.125f);  // k->P0
    conv_silu_kernel<<<nconv, blk, 0, stream>>>(P2, vcw, vcb, P1, 1.f);     // v->P1
    gemm_bt<3, false><<<g8, blk, 0, stream>>>(xb, Wg, nullptr, nullptr, P2, M, HID, HID); // g->P2
    gemm_bt<5, false><<<dim3(1, 32), blk, 0, stream>>>(xb, Wb, bb, betab, nullptr, M, 16, HID);
    kk_kernel<<<1024, blk, 0, stream>>>(P0, betab, gkk);
    scan_kernel<<<512, dim3(64), 0, stream>>>(P4, P0, P1, P3, betab, gkk, ob);
    ln_gate_kernel<<<M * 16 / 4, blk, 0, stream>>>(ob, P2, lnw, lnb, P3);   // ->P3
    gemm_bt<4, false><<<g8, blk, 0, stream>>>(P3, Wo, nullptr, outf, nullptr, M, HID, HID);
  } else {
    bf16* P  = (bf16*)(ws);
    bf16* qb = (bf16*)(ws + PB);
    bf16* kb = (bf16*)(ws + 2 * PB);
    bf16* vb = (bf16*)(ws + 3 * PB);

    gemm_bt<2, true><<<g8, blk, 0, stream>>>(x, Wq, nullptr, nullptr, P, M, HID, HID);
    conv_silu_kernel<<<nconv, blk, 0, stream>>>(P, qcw, qcb, qb, 1.f);
    gemm_bt<2, true><<<g8, blk, 0, stream>>>(x, Wk, nullptr, nullptr, P, M, HID, HID);
    conv_silu_kernel<<<nconv, blk, 0, stream>>>(P, kcw, kcb, kb, 0.125f);
    gemm_bt<2, true><<<g8, blk, 0, stream>>>(x, Wv, nullptr, nullptr, P, M, HID, HID);
    conv_silu_kernel<<<nconv, blk, 0, stream>>>(P, vcw, vcb, vb, 1.f);
    gemm_bt<3, true><<<g8, blk, 0, stream>>>(x, Wa, ba, nullptr, P, M, HID, HID);
    gemm_bt<5, true><<<dim3(1, 32), blk, 0, stream>>>(x, Wb, bb, betab, nullptr, M, 16, HID);
    kk_kernel<<<1024, blk, 0, stream>>>(kb, betab, gkk);
    scan_kernel<<<512, dim3(64), 0, stream>>>(qb, kb, vb, P, betab, gkk, ob);
    gemm_bt<3, true><<<g8, blk, 0, stream>>>(x, Wg, nullptr, nullptr, qb, M, HID, HID);
    ln_gate_kernel<<<M * 16 / 4, blk, 0, stream>>>(ob, qb, lnw, lnb, kb);
    gemm_bt<4, false><<<g8, blk, 0, stream>>>(kb, Wo, nullptr, outf, nullptr, M, HID, HID);
  }
}